// Round 1
// baseline (1615.044 us; speedup 1.0000x reference)
//
#include <hip/hip_runtime.h>
#include <math.h>

// Problem constants (from reference): NUM_Q=64, RANK=64, DIM=768, NH=8, DH=96,
// NUM_Q*RANK=4096. b and n derived from in_sizes at launch (b=4, n=1024).

// ---------------------------------------------------------------------------
// Generic fp32 tiled GEMM: C[M,N] = A[M,K] @ B[K,N]. M,N,K all % 32 == 0.
// Block = (32,8) threads, 32x32 C-tile, each thread computes 4 rows.
// ---------------------------------------------------------------------------
__global__ void gemm32(const float* __restrict__ A, const float* __restrict__ B,
                       float* __restrict__ C, int M, int N, int K) {
    __shared__ float As[32][33];
    __shared__ float Bs[32][33];
    const int tx = threadIdx.x;           // 0..31
    const int ty = threadIdx.y;           // 0..7
    const int row0 = blockIdx.y * 32;
    const int col0 = blockIdx.x * 32;

    float acc[4] = {0.f, 0.f, 0.f, 0.f};

    for (int k0 = 0; k0 < K; k0 += 32) {
#pragma unroll
        for (int i = 0; i < 4; i++) {
            As[ty + 8 * i][tx] = A[(size_t)(row0 + ty + 8 * i) * K + k0 + tx];
            Bs[ty + 8 * i][tx] = B[(size_t)(k0 + ty + 8 * i) * N + col0 + tx];
        }
        __syncthreads();
#pragma unroll
        for (int kk = 0; kk < 32; kk++) {
            const float bv = Bs[kk][tx];
#pragma unroll
            for (int i = 0; i < 4; i++)
                acc[i] += As[ty + 8 * i][kk] * bv;
        }
        __syncthreads();
    }
#pragma unroll
    for (int i = 0; i < 4; i++)
        C[(size_t)(row0 + ty + 8 * i) * N + col0 + tx] = acc[i];
}

// ---------------------------------------------------------------------------
// LayerNorm over 4096-wide rows, in place. One block (256 thr) per row.
// Two-pass (mean, then var of centered values) with row cached in registers.
// ---------------------------------------------------------------------------
__global__ void layernorm4096(float* __restrict__ h1,
                              const float* __restrict__ g,
                              const float* __restrict__ bta) {
    const int row = blockIdx.x;
    const int tid = threadIdx.x;
    float* p = h1 + (size_t)row * 4096;

    float vals[16];
    float s = 0.f;
#pragma unroll
    for (int i = 0; i < 16; i++) {
        vals[i] = p[i * 256 + tid];
        s += vals[i];
    }

    __shared__ float red[256];
    red[tid] = s;
    __syncthreads();
    for (int off = 128; off > 0; off >>= 1) {
        if (tid < off) red[tid] += red[tid + off];
        __syncthreads();
    }
    const float mu = red[0] * (1.0f / 4096.0f);
    __syncthreads();

    float s2 = 0.f;
#pragma unroll
    for (int i = 0; i < 16; i++) {
        const float d = vals[i] - mu;
        s2 += d * d;
    }
    red[tid] = s2;
    __syncthreads();
    for (int off = 128; off > 0; off >>= 1) {
        if (tid < off) red[tid] += red[tid + off];
        __syncthreads();
    }
    const float var = red[0] * (1.0f / 4096.0f);
    const float rstd = rsqrtf(var + 1e-5f);

#pragma unroll
    for (int i = 0; i < 16; i++) {
        const int c = i * 256 + tid;
        p[c] = (vals[i] - mu) * rstd * g[c] + bta[c];
    }
}

// ---------------------------------------------------------------------------
// Attention scores + softmax. One block (256 thr) per (b,h,qi).
// sim = (q*s)·(k*s) = dot/sqrt(96); softmax over n keys (n <= 1024).
// ---------------------------------------------------------------------------
__global__ void attn_softmax(const float* __restrict__ q,
                             const float* __restrict__ k,
                             float* __restrict__ attn, int n) {
    const int bid = blockIdx.x;
    const int qi = bid & 63;
    const int h = (bid >> 6) & 7;
    const int b = bid >> 9;
    const int tid = threadIdx.x;

    __shared__ float qv[96];
    __shared__ float sc[1024];
    __shared__ float red[256];

    if (tid < 96) qv[tid] = q[((size_t)(b * 64 + qi)) * 768 + h * 96 + tid];
    __syncthreads();

    const float scale = 0.10206207261596575f;  // 1/sqrt(96)

    float m = -1e30f;
    for (int ni = tid; ni < n; ni += 256) {
        const float* kp = k + ((size_t)b * n + ni) * 768 + h * 96;
        float dot = 0.f;
#pragma unroll
        for (int d = 0; d < 96; d++) dot += qv[d] * kp[d];
        dot *= scale;
        sc[ni] = dot;
        m = fmaxf(m, dot);
    }
    red[tid] = m;
    __syncthreads();
    for (int off = 128; off > 0; off >>= 1) {
        if (tid < off) red[tid] = fmaxf(red[tid], red[tid + off]);
        __syncthreads();
    }
    const float mx = red[0];
    __syncthreads();

    float ssum = 0.f;
    for (int ni = tid; ni < n; ni += 256) {
        const float e = expf(sc[ni] - mx);
        sc[ni] = e;
        ssum += e;
    }
    red[tid] = ssum;
    __syncthreads();
    for (int off = 128; off > 0; off >>= 1) {
        if (tid < off) red[tid] += red[tid + off];
        __syncthreads();
    }
    const float inv = 1.0f / red[0];

    float* ap = attn + (((size_t)(b * 8 + h) * 64 + qi)) * n;
    for (int ni = tid; ni < n; ni += 256) ap[ni] = sc[ni] * inv;
}

// ---------------------------------------------------------------------------
// A[b,qi,h,r] = sum_n attn[b,h,qi,n] * vmid[b,n,qi*64+r]
// One block (512 thr: h=tid>>6, r=tid&63) per (b,qi). Reads the h1 column
// block for (b,qi) exactly once, coalesced across r.
// ---------------------------------------------------------------------------
__global__ void attn_vmid_reduce(const float* __restrict__ attn,
                                 const float* __restrict__ vmid,
                                 float* __restrict__ Abuf, int n) {
    const int b = blockIdx.x >> 6;
    const int qi = blockIdx.x & 63;
    const int tid = threadIdx.x;
    const int h = tid >> 6;
    const int r = tid & 63;

    __shared__ float sA[8 * 1024];  // 32 KB (n <= 1024)
    for (int i = tid; i < 8 * n; i += 512) {
        const int hh = i / n;
        const int ni = i - hh * n;
        sA[hh * n + ni] = attn[(((size_t)(b * 8 + hh) * 64 + qi)) * n + ni];
    }
    __syncthreads();

    const float* vp = vmid + (size_t)b * n * 4096 + qi * 64 + r;
    const float* ap = sA + h * n;
    float acc = 0.f;
#pragma unroll 4
    for (int ni = 0; ni < n; ni++) acc += ap[ni] * vp[(size_t)ni * 4096];

    Abuf[(size_t)blockIdx.x * 512 + h * 64 + r] = acc;
}

// ---------------------------------------------------------------------------
// out_pre[b,qi,d] = sum_r A[b,qi,h(d),r] * Wc[qi,r,d], h(d)=d/96.
// One block (768 thr) per (b,qi); Wc reads coalesced across d.
// ---------------------------------------------------------------------------
__global__ void apply_wc(const float* __restrict__ Abuf,
                         const float* __restrict__ Wc,
                         float* __restrict__ out_pre) {
    const int qi = blockIdx.x & 63;
    const int d = threadIdx.x;

    __shared__ float sA[512];
    if (d < 512) sA[d] = Abuf[(size_t)blockIdx.x * 512 + d];
    __syncthreads();

    const int h = d / 96;
    const float* wp = Wc + (size_t)qi * 64 * 768 + d;
    float acc = 0.f;
#pragma unroll
    for (int r = 0; r < 64; r++) acc += sA[h * 64 + r] * wp[(size_t)r * 768];

    out_pre[(size_t)blockIdx.x * 768 + d] = acc;
}

// ---------------------------------------------------------------------------
extern "C" void kernel_launch(void* const* d_in, const int* in_sizes, int n_in,
                              void* d_out, int out_size, void* d_ws, size_t ws_size,
                              hipStream_t stream) {
    const float* x       = (const float*)d_in[0];
    const float* context = (const float*)d_in[1];
    const float* Wq      = (const float*)d_in[2];
    const float* Wk      = (const float*)d_in[3];
    const float* Wv1     = (const float*)d_in[4];
    const float* ln_g    = (const float*)d_in[5];
    const float* ln_b    = (const float*)d_in[6];
    const float* Wc      = (const float*)d_in[7];
    const float* Wout    = (const float*)d_in[8];
    float* out = (float*)d_out;

    const int b = in_sizes[0] / (64 * 768);
    const int n = in_sizes[1] / (b * 768);

    float* ws = (float*)d_ws;
    size_t off = 0;
    float* qbuf = ws + off;  off += (size_t)b * 64 * 768;
    float* kbuf = ws + off;  off += (size_t)b * n * 768;
    float* h1   = ws + off;  off += (size_t)b * n * 4096;
    float* attn = ws + off;  off += (size_t)b * 8 * 64 * n;
    float* Abuf = ws + off;  off += (size_t)b * 64 * 512;
    float* outp = ws + off;  off += (size_t)b * 64 * 768;

    const dim3 blk(32, 8);

    // q = x @ Wq            [b*64, 768]
    gemm32<<<dim3(768 / 32, (b * 64) / 32), blk, 0, stream>>>(x, Wq, qbuf, b * 64, 768, 768);
    // k = context @ Wk      [b*n, 768]
    gemm32<<<dim3(768 / 32, (b * n) / 32), blk, 0, stream>>>(context, Wk, kbuf, b * n, 768, 768);
    // h1 = context @ Wv1    [b*n, 4096]
    gemm32<<<dim3(4096 / 32, (b * n) / 32), blk, 0, stream>>>(context, Wv1, h1, b * n, 4096, 768);
    // LayerNorm (in place) -> vmid
    layernorm4096<<<b * n, 256, 0, stream>>>(h1, ln_g, ln_b);
    // scores + softmax -> attn[b,h,qi,n]
    attn_softmax<<<b * 8 * 64, 256, 0, stream>>>(qbuf, kbuf, attn, n);
    // A[b,qi,h,r] = attn · vmid
    attn_vmid_reduce<<<b * 64, 512, 0, stream>>>(attn, h1, Abuf, n);
    // out_pre = A · Wc
    apply_wc<<<b * 64, 768, 0, stream>>>(Abuf, Wc, outp);
    // out = out_pre @ Wout
    gemm32<<<dim3(768 / 32, (b * 64) / 32), blk, 0, stream>>>(outp, Wout, out, b * 64, 768, 768);
}

// Round 3
// 392.854 us; speedup vs baseline: 4.1111x; 4.1111x over previous
//
#include <hip/hip_runtime.h>
#include <math.h>

typedef unsigned short ushort_t;
typedef __bf16 bf16x8 __attribute__((ext_vector_type(8)));
typedef float f32x4 __attribute__((ext_vector_type(4)));

// ---------------------------------------------------------------------------
// fp32 -> bf16 (RNE), flat, vectorized: one float4 per thread.
// ---------------------------------------------------------------------------
__device__ __forceinline__ ushort_t f2b_rne(float f) {
    union { float f; unsigned int u; } c;
    c.f = f;
    unsigned int u = c.u;
    u += 0x7FFFu + ((u >> 16) & 1u);
    return (ushort_t)(u >> 16);
}

__global__ void f2b_flat(const float* __restrict__ in, ushort_t* __restrict__ out, int n4) {
    int i = blockIdx.x * blockDim.x + threadIdx.x;
    if (i >= n4) return;
    float4 v = ((const float4*)in)[i];
    ushort_t o[4] = {f2b_rne(v.x), f2b_rne(v.y), f2b_rne(v.z), f2b_rne(v.w)};
    *(uint2*)&out[(size_t)i * 4] = *(uint2*)o;
}

// ---------------------------------------------------------------------------
// fp32 [R,C] -> bf16 [C,R] (transpose + convert). Block (32,8), 32x32 tiles.
// ---------------------------------------------------------------------------
__global__ void f2b_t(const float* __restrict__ in, ushort_t* __restrict__ out,
                      int R, int C) {
    __shared__ float t[32][33];
    const int tx = threadIdx.x, ty = threadIdx.y;
    const int r0 = blockIdx.y * 32, c0 = blockIdx.x * 32;
#pragma unroll
    for (int i = 0; i < 4; i++)
        t[ty + 8 * i][tx] = in[(size_t)(r0 + ty + 8 * i) * C + c0 + tx];
    __syncthreads();
#pragma unroll
    for (int i = 0; i < 4; i++)
        out[(size_t)(c0 + ty + 8 * i) * R + r0 + tx] = f2b_rne(t[tx][ty + 8 * i]);
}

// ---------------------------------------------------------------------------
// bf16 MFMA GEMM: C[M,N] (fp32) = A[M,K] (bf16) @ Bt[N,K]^T (bf16).
// 128x128 C-tile / block, 256 thr = 4 waves (2x2 of 64x64), BK=32,
// mfma_f32_16x16x32_bf16. Each thread stages TWO 8-elem granules per operand
// (rows srow and srow+64) => full 128x32 slab coverage (round-2 bug fix).
// M%128==0, N%128==0, K%32==0.
// ---------------------------------------------------------------------------
__global__ __launch_bounds__(256) void gemm_bt(const ushort_t* __restrict__ A,
                                               const ushort_t* __restrict__ Bt,
                                               float* __restrict__ C,
                                               int M, int N, int K) {
    // Row stride 40 elem = 80 B = 5 x 16B granules (coprime with 8 banks-of-16B):
    // fragment ds_read_b128 across 16 lanes -> 2-way conflict = free (m136).
    __shared__ ushort_t As[128 * 40];
    __shared__ ushort_t Bs[128 * 40];

    const int t = threadIdx.x;
    const int lane = t & 63;
    const int wave = t >> 6;
    const int quad = lane >> 4;
    const int l15 = lane & 15;
    const int wm = (wave >> 1) * 64;   // wave row base within tile
    const int wn = (wave & 1) * 64;    // wave col base within tile
    const int row0 = blockIdx.y * 128, col0 = blockIdx.x * 128;

    const int srow = t >> 2;           // 0..63
    const int sseg = t & 3;            // 0..3  (16B segment within 32-elem slab)
    const ushort_t* ga0 = A + (size_t)(row0 + srow) * K + sseg * 8;
    const ushort_t* ga1 = A + (size_t)(row0 + srow + 64) * K + sseg * 8;
    const ushort_t* gb0 = Bt + (size_t)(col0 + srow) * K + sseg * 8;
    const ushort_t* gb1 = Bt + (size_t)(col0 + srow + 64) * K + sseg * 8;

    f32x4 acc[4][4] = {};

    bf16x8 ra0 = *(const bf16x8*)ga0;
    bf16x8 ra1 = *(const bf16x8*)ga1;
    bf16x8 rb0 = *(const bf16x8*)gb0;
    bf16x8 rb1 = *(const bf16x8*)gb1;

    for (int k0 = 0; k0 < K; k0 += 32) {
        __syncthreads();
        *(bf16x8*)&As[srow * 40 + sseg * 8] = ra0;
        *(bf16x8*)&As[(srow + 64) * 40 + sseg * 8] = ra1;
        *(bf16x8*)&Bs[srow * 40 + sseg * 8] = rb0;
        *(bf16x8*)&Bs[(srow + 64) * 40 + sseg * 8] = rb1;
        __syncthreads();
        if (k0 + 32 < K) {  // prefetch next K-slab; overlaps with MFMAs below
            ra0 = *(const bf16x8*)(ga0 + k0 + 32);
            ra1 = *(const bf16x8*)(ga1 + k0 + 32);
            rb0 = *(const bf16x8*)(gb0 + k0 + 32);
            rb1 = *(const bf16x8*)(gb1 + k0 + 32);
        }
        bf16x8 af[4], bfr[4];
#pragma unroll
        for (int i = 0; i < 4; i++)
            af[i] = *(const bf16x8*)&As[(wm + i * 16 + l15) * 40 + quad * 8];
#pragma unroll
        for (int j = 0; j < 4; j++)
            bfr[j] = *(const bf16x8*)&Bs[(wn + j * 16 + l15) * 40 + quad * 8];
#pragma unroll
        for (int i = 0; i < 4; i++)
#pragma unroll
            for (int j = 0; j < 4; j++)
                acc[i][j] = __builtin_amdgcn_mfma_f32_16x16x32_bf16(
                    af[i], bfr[j], acc[i][j], 0, 0, 0);
    }

    // C/D layout: col = lane&15, row = (lane>>4)*4 + reg   [m89/m91]
#pragma unroll
    for (int i = 0; i < 4; i++)
#pragma unroll
        for (int j = 0; j < 4; j++)
#pragma unroll
            for (int r = 0; r < 4; r++) {
                const int row = row0 + wm + i * 16 + quad * 4 + r;
                const int col = col0 + wn + j * 16 + l15;
                C[(size_t)row * N + col] = acc[i][j][r];
            }
}

// ---------------------------------------------------------------------------
// LayerNorm over 4096-wide rows, in place, float4-vectorized.
// ---------------------------------------------------------------------------
__global__ void layernorm4096(float* __restrict__ h1,
                              const float* __restrict__ g,
                              const float* __restrict__ bta) {
    const int row = blockIdx.x;
    const int tid = threadIdx.x;
    float4* p = (float4*)(h1 + (size_t)row * 4096);
    const float4* g4 = (const float4*)g;
    const float4* b4 = (const float4*)bta;

    float4 vals[4];
    float s = 0.f;
#pragma unroll
    for (int i = 0; i < 4; i++) {
        vals[i] = p[i * 256 + tid];
        s += vals[i].x + vals[i].y + vals[i].z + vals[i].w;
    }

    __shared__ float red[256];
    red[tid] = s;
    __syncthreads();
    for (int off = 128; off > 0; off >>= 1) {
        if (tid < off) red[tid] += red[tid + off];
        __syncthreads();
    }
    const float mu = red[0] * (1.0f / 4096.0f);
    __syncthreads();

    float s2 = 0.f;
#pragma unroll
    for (int i = 0; i < 4; i++) {
        float dx = vals[i].x - mu, dy = vals[i].y - mu,
              dz = vals[i].z - mu, dw = vals[i].w - mu;
        s2 += dx * dx + dy * dy + dz * dz + dw * dw;
    }
    red[tid] = s2;
    __syncthreads();
    for (int off = 128; off > 0; off >>= 1) {
        if (tid < off) red[tid] += red[tid + off];
        __syncthreads();
    }
    const float rstd = rsqrtf(red[0] * (1.0f / 4096.0f) + 1e-5f);

#pragma unroll
    for (int i = 0; i < 4; i++) {
        const int c = i * 256 + tid;
        float4 gv = g4[c], bv = b4[c], o;
        o.x = (vals[i].x - mu) * rstd * gv.x + bv.x;
        o.y = (vals[i].y - mu) * rstd * gv.y + bv.y;
        o.z = (vals[i].z - mu) * rstd * gv.z + bv.z;
        o.w = (vals[i].w - mu) * rstd * gv.w + bv.w;
        p[c] = o;
    }
}

// ---------------------------------------------------------------------------
// Attention scores + softmax. One block (256 thr) per (b,h,qi).
// ---------------------------------------------------------------------------
__global__ void attn_softmax(const float* __restrict__ q,
                             const float* __restrict__ k,
                             float* __restrict__ attn, int n) {
    const int bid = blockIdx.x;
    const int qi = bid & 63;
    const int h = (bid >> 6) & 7;
    const int b = bid >> 9;
    const int tid = threadIdx.x;

    __shared__ float qv[96];
    __shared__ float sc[1024];
    __shared__ float red[256];

    if (tid < 96) qv[tid] = q[((size_t)(b * 64 + qi)) * 768 + h * 96 + tid];
    __syncthreads();

    const float scale = 0.10206207261596575f;  // 1/sqrt(96)

    float m = -1e30f;
    for (int ni = tid; ni < n; ni += 256) {
        const float4* kp = (const float4*)(k + ((size_t)b * n + ni) * 768 + h * 96);
        float dot = 0.f;
#pragma unroll
        for (int d = 0; d < 24; d++) {
            float4 kv = kp[d];
            dot += qv[4 * d] * kv.x + qv[4 * d + 1] * kv.y +
                   qv[4 * d + 2] * kv.z + qv[4 * d + 3] * kv.w;
        }
        dot *= scale;
        sc[ni] = dot;
        m = fmaxf(m, dot);
    }
    red[tid] = m;
    __syncthreads();
    for (int off = 128; off > 0; off >>= 1) {
        if (tid < off) red[tid] = fmaxf(red[tid], red[tid + off]);
        __syncthreads();
    }
    const float mx = red[0];
    __syncthreads();

    float ssum = 0.f;
    for (int ni = tid; ni < n; ni += 256) {
        const float e = expf(sc[ni] - mx);
        sc[ni] = e;
        ssum += e;
    }
    red[tid] = ssum;
    __syncthreads();
    for (int off = 128; off > 0; off >>= 1) {
        if (tid < off) red[tid] += red[tid + off];
        __syncthreads();
    }
    const float inv = 1.0f / red[0];

    float* ap = attn + (((size_t)(b * 8 + h) * 64 + qi)) * n;
    for (int ni = tid; ni < n; ni += 256) ap[ni] = sc[ni] * inv;
}

// ---------------------------------------------------------------------------
// A[b,qi,h,r] = sum_n attn[b,h,qi,n] * vmid[b,n,qi*64+r]
// ---------------------------------------------------------------------------
__global__ void attn_vmid_reduce(const float* __restrict__ attn,
                                 const float* __restrict__ vmid,
                                 float* __restrict__ Abuf, int n) {
    const int b = blockIdx.x >> 6;
    const int qi = blockIdx.x & 63;
    const int tid = threadIdx.x;
    const int h = tid >> 6;
    const int r = tid & 63;

    __shared__ float sA[8 * 1024];
    for (int i = tid; i < 8 * n; i += 512) {
        const int hh = i / n;
        const int ni = i - hh * n;
        sA[hh * n + ni] = attn[(((size_t)(b * 8 + hh) * 64 + qi)) * n + ni];
    }
    __syncthreads();

    const float* vp = vmid + (size_t)b * n * 4096 + qi * 64 + r;
    const float* ap = sA + h * n;
    float acc = 0.f;
#pragma unroll 4
    for (int ni = 0; ni < n; ni++) acc += ap[ni] * vp[(size_t)ni * 4096];

    Abuf[(size_t)blockIdx.x * 512 + h * 64 + r] = acc;
}

// ---------------------------------------------------------------------------
// out_pre[b,qi,d] = sum_r A[b,qi,h(d),r] * Wc[qi,r,d]  (bf16 output)
// ---------------------------------------------------------------------------
__global__ void apply_wc(const float* __restrict__ Abuf,
                         const float* __restrict__ Wc,
                         ushort_t* __restrict__ out_pre) {
    const int qi = blockIdx.x & 63;
    const int d = threadIdx.x;

    __shared__ float sA[512];
    if (d < 512) sA[d] = Abuf[(size_t)blockIdx.x * 512 + d];
    __syncthreads();

    const int h = d / 96;
    const float* wp = Wc + (size_t)qi * 64 * 768 + d;
    float acc = 0.f;
#pragma unroll
    for (int r = 0; r < 64; r++) acc += sA[h * 64 + r] * wp[(size_t)r * 768];

    out_pre[(size_t)blockIdx.x * 768 + d] = f2b_rne(acc);
}

// ---------------------------------------------------------------------------
extern "C" void kernel_launch(void* const* d_in, const int* in_sizes, int n_in,
                              void* d_out, int out_size, void* d_ws, size_t ws_size,
                              hipStream_t stream) {
    const float* x       = (const float*)d_in[0];
    const float* context = (const float*)d_in[1];
    const float* Wq      = (const float*)d_in[2];
    const float* Wk      = (const float*)d_in[3];
    const float* Wv1     = (const float*)d_in[4];
    const float* ln_g    = (const float*)d_in[5];
    const float* ln_b    = (const float*)d_in[6];
    const float* Wc      = (const float*)d_in[7];
    const float* Wout    = (const float*)d_in[8];
    float* out = (float*)d_out;

    const int b = in_sizes[0] / (64 * 768);
    const int n = in_sizes[1] / (b * 768);
    const int M  = b * 64;    // 256
    const int Mn = b * n;     // 4096

    float* ws = (float*)d_ws;
    size_t off = 0;
    float* qbuf = ws + off;  off += (size_t)M * 768;
    float* kbuf = ws + off;  off += (size_t)Mn * 768;
    float* h1   = ws + off;  off += (size_t)Mn * 4096;
    float* attn = ws + off;  off += (size_t)b * 8 * 64 * n;
    float* Abuf = ws + off;  off += (size_t)M * 512;

    ushort_t* us = (ushort_t*)(ws + off);
    size_t uo = 0;
    ushort_t* x_b    = us + uo;  uo += (size_t)M * 768;
    ushort_t* ctx_b  = us + uo;  uo += (size_t)Mn * 768;
    ushort_t* Wq_t   = us + uo;  uo += (size_t)768 * 768;
    ushort_t* Wk_t   = us + uo;  uo += (size_t)768 * 768;
    ushort_t* Wv1_t  = us + uo;  uo += (size_t)4096 * 768;
    ushort_t* Wout_t = us + uo;  uo += (size_t)768 * 768;
    ushort_t* outp_b = us + uo;  uo += (size_t)M * 768;

    const dim3 tblk(32, 8);

    // Convert activations (flat) and weights (transposed) to bf16.
    {
        int n4 = M * 768 / 4;
        f2b_flat<<<(n4 + 255) / 256, 256, 0, stream>>>(x, x_b, n4);
        n4 = Mn * 768 / 4;
        f2b_flat<<<(n4 + 255) / 256, 256, 0, stream>>>(context, ctx_b, n4);
        f2b_t<<<dim3(768 / 32, 768 / 32), tblk, 0, stream>>>(Wq, Wq_t, 768, 768);
        f2b_t<<<dim3(768 / 32, 768 / 32), tblk, 0, stream>>>(Wk, Wk_t, 768, 768);
        f2b_t<<<dim3(4096 / 32, 768 / 32), tblk, 0, stream>>>(Wv1, Wv1_t, 768, 4096);
        f2b_t<<<dim3(768 / 32, 768 / 32), tblk, 0, stream>>>(Wout, Wout_t, 768, 768);
    }

    // q = x @ Wq
    gemm_bt<<<dim3(768 / 128, M / 128), 256, 0, stream>>>(x_b, Wq_t, qbuf, M, 768, 768);
    // k = context @ Wk
    gemm_bt<<<dim3(768 / 128, Mn / 128), 256, 0, stream>>>(ctx_b, Wk_t, kbuf, Mn, 768, 768);
    // h1 = context @ Wv1
    gemm_bt<<<dim3(4096 / 128, Mn / 128), 256, 0, stream>>>(ctx_b, Wv1_t, h1, Mn, 4096, 768);
    // LayerNorm in place -> vmid
    layernorm4096<<<Mn, 256, 0, stream>>>(h1, ln_g, ln_b);
    // scores + softmax
    attn_softmax<<<b * 8 * 64, 256, 0, stream>>>(qbuf, kbuf, attn, n);
    // A = attn . vmid
    attn_vmid_reduce<<<b * 64, 512, 0, stream>>>(attn, h1, Abuf, n);
    // out_pre = A . Wc (bf16 out)
    apply_wc<<<b * 64, 768, 0, stream>>>(Abuf, Wc, outp_b);
    // out = out_pre @ Wout
    gemm_bt<<<dim3(768 / 128, M / 128), 256, 0, stream>>>(outp_b, Wout_t, out, M, 768, 768);
}

// Round 4
// 264.709 us; speedup vs baseline: 6.1012x; 1.4841x over previous
//
#include <hip/hip_runtime.h>
#include <math.h>

typedef unsigned short ushort_t;
typedef __bf16 bf16x8 __attribute__((ext_vector_type(8)));
typedef float f32x4 __attribute__((ext_vector_type(4)));

// ---------------------------------------------------------------------------
// fp32 -> bf16 (RNE)
// ---------------------------------------------------------------------------
__device__ __forceinline__ ushort_t f2b_rne(float f) {
    union { float f; unsigned int u; } c;
    c.f = f;
    unsigned int u = c.u;
    u += 0x7FFFu + ((u >> 16) & 1u);
    return (ushort_t)(u >> 16);
}

__global__ void f2b_flat(const float* __restrict__ in, ushort_t* __restrict__ out, int n4) {
    int i = blockIdx.x * blockDim.x + threadIdx.x;
    if (i >= n4) return;
    float4 v = ((const float4*)in)[i];
    ushort_t o[4] = {f2b_rne(v.x), f2b_rne(v.y), f2b_rne(v.z), f2b_rne(v.w)};
    *(uint2*)&out[(size_t)i * 4] = *(uint2*)o;
}

// fp32 [R,C] -> bf16 [C,R] (transpose + convert)
__global__ void f2b_t(const float* __restrict__ in, ushort_t* __restrict__ out,
                      int R, int C) {
    __shared__ float t[32][33];
    const int tx = threadIdx.x, ty = threadIdx.y;
    const int r0 = blockIdx.y * 32, c0 = blockIdx.x * 32;
#pragma unroll
    for (int i = 0; i < 4; i++)
        t[ty + 8 * i][tx] = in[(size_t)(r0 + ty + 8 * i) * C + c0 + tx];
    __syncthreads();
#pragma unroll
    for (int i = 0; i < 4; i++)
        out[(size_t)(c0 + ty + 8 * i) * R + r0 + tx] = f2b_rne(t[tx][ty + 8 * i]);
}

// ---------------------------------------------------------------------------
// bf16 MFMA GEMM: C[M,N] = A[M,K] @ Bt[N,K]^T. 128x128 tile, 4 waves, BK=32.
// BF16OUT selects fp32 or bf16 output.
// ---------------------------------------------------------------------------
template <bool BF16OUT>
__global__ __launch_bounds__(256) void gemm_bt(const ushort_t* __restrict__ A,
                                               const ushort_t* __restrict__ Bt,
                                               void* __restrict__ Cout,
                                               int M, int N, int K) {
    __shared__ ushort_t As[128 * 40];  // stride 40 elem = 5x16B granules: 2-way=free
    __shared__ ushort_t Bs[128 * 40];

    const int t = threadIdx.x;
    const int lane = t & 63;
    const int wave = t >> 6;
    const int quad = lane >> 4;
    const int l15 = lane & 15;
    const int wm = (wave >> 1) * 64;
    const int wn = (wave & 1) * 64;
    const int row0 = blockIdx.y * 128, col0 = blockIdx.x * 128;

    const int srow = t >> 2;  // 0..63
    const int sseg = t & 3;   // 0..3
    const ushort_t* ga0 = A + (size_t)(row0 + srow) * K + sseg * 8;
    const ushort_t* ga1 = A + (size_t)(row0 + srow + 64) * K + sseg * 8;
    const ushort_t* gb0 = Bt + (size_t)(col0 + srow) * K + sseg * 8;
    const ushort_t* gb1 = Bt + (size_t)(col0 + srow + 64) * K + sseg * 8;

    f32x4 acc[4][4] = {};

    bf16x8 ra0 = *(const bf16x8*)ga0;
    bf16x8 ra1 = *(const bf16x8*)ga1;
    bf16x8 rb0 = *(const bf16x8*)gb0;
    bf16x8 rb1 = *(const bf16x8*)gb1;

    for (int k0 = 0; k0 < K; k0 += 32) {
        __syncthreads();
        *(bf16x8*)&As[srow * 40 + sseg * 8] = ra0;
        *(bf16x8*)&As[(srow + 64) * 40 + sseg * 8] = ra1;
        *(bf16x8*)&Bs[srow * 40 + sseg * 8] = rb0;
        *(bf16x8*)&Bs[(srow + 64) * 40 + sseg * 8] = rb1;
        __syncthreads();
        if (k0 + 32 < K) {
            ra0 = *(const bf16x8*)(ga0 + k0 + 32);
            ra1 = *(const bf16x8*)(ga1 + k0 + 32);
            rb0 = *(const bf16x8*)(gb0 + k0 + 32);
            rb1 = *(const bf16x8*)(gb1 + k0 + 32);
        }
        bf16x8 af[4], bfr[4];
#pragma unroll
        for (int i = 0; i < 4; i++)
            af[i] = *(const bf16x8*)&As[(wm + i * 16 + l15) * 40 + quad * 8];
#pragma unroll
        for (int j = 0; j < 4; j++)
            bfr[j] = *(const bf16x8*)&Bs[(wn + j * 16 + l15) * 40 + quad * 8];
#pragma unroll
        for (int i = 0; i < 4; i++)
#pragma unroll
            for (int j = 0; j < 4; j++)
                acc[i][j] = __builtin_amdgcn_mfma_f32_16x16x32_bf16(
                    af[i], bfr[j], acc[i][j], 0, 0, 0);
    }

    // C/D layout: col = lane&15, row = (lane>>4)*4 + reg   [m89/m91]
#pragma unroll
    for (int i = 0; i < 4; i++)
#pragma unroll
        for (int j = 0; j < 4; j++)
#pragma unroll
            for (int r = 0; r < 4; r++) {
                const int row = row0 + wm + i * 16 + quad * 4 + r;
                const int col = col0 + wn + j * 16 + l15;
                if (BF16OUT)
                    ((ushort_t*)Cout)[(size_t)row * N + col] = f2b_rne(acc[i][j][r]);
                else
                    ((float*)Cout)[(size_t)row * N + col] = acc[i][j][r];
            }
}

// ---------------------------------------------------------------------------
// Scores via MFMA: S[b,h,64,n] = (Q_h @ K_h^T) / sqrt(96), bf16 in, fp32 out.
// Block: (ntile of 128 cols) x (b*8+h). 256 thr = 4 waves (2x2 of 32x64).
// K=96 staged once (no K-loop). LDS row stride 104 elem = 13x16B (odd) ->
// fragment ds_read_b128 2-way conflict = free (m136).
// ---------------------------------------------------------------------------
__global__ __launch_bounds__(256) void scores_mfma(const ushort_t* __restrict__ qb,
                                                   const ushort_t* __restrict__ kb,
                                                   float* __restrict__ S, int n) {
    const int bh = blockIdx.y;
    const int b = bh >> 3, h = bh & 7;
    const int n0 = blockIdx.x * 128;
    const int t = threadIdx.x;
    const int lane = t & 63, wave = t >> 6;
    const int quad = lane >> 4, l15 = lane & 15;
    const int wm = (wave >> 1) * 32;
    const int wn = (wave & 1) * 64;

    __shared__ ushort_t Qs[64 * 104];
    __shared__ ushort_t Ks[128 * 104];

    for (int g = t; g < 768; g += 256) {           // 64 rows x 12 granules
        const int r = g / 12, s = g - r * 12;
        *(bf16x8*)&Qs[r * 104 + s * 8] =
            *(const bf16x8*)&qb[(size_t)(b * 64 + r) * 768 + h * 96 + s * 8];
    }
    for (int g = t; g < 1536; g += 256) {          // 128 rows x 12 granules
        const int r = g / 12, s = g - r * 12;
        *(bf16x8*)&Ks[r * 104 + s * 8] =
            *(const bf16x8*)&kb[(size_t)(b * n + n0 + r) * 768 + h * 96 + s * 8];
    }
    __syncthreads();

    f32x4 acc[2][4] = {};
#pragma unroll
    for (int ks = 0; ks < 3; ks++) {
        bf16x8 af[2], bfr[4];
#pragma unroll
        for (int i = 0; i < 2; i++)
            af[i] = *(const bf16x8*)&Qs[(wm + i * 16 + l15) * 104 + ks * 32 + quad * 8];
#pragma unroll
        for (int j = 0; j < 4; j++)
            bfr[j] = *(const bf16x8*)&Ks[(wn + j * 16 + l15) * 104 + ks * 32 + quad * 8];
#pragma unroll
        for (int i = 0; i < 2; i++)
#pragma unroll
            for (int j = 0; j < 4; j++)
                acc[i][j] = __builtin_amdgcn_mfma_f32_16x16x32_bf16(
                    af[i], bfr[j], acc[i][j], 0, 0, 0);
    }

    const float sc = 0.10206207261596575f;  // 1/sqrt(96)
    float* Sp = S + (size_t)bh * 64 * n;
#pragma unroll
    for (int i = 0; i < 2; i++)
#pragma unroll
        for (int j = 0; j < 4; j++)
#pragma unroll
            for (int r = 0; r < 4; r++) {
                const int row = wm + i * 16 + quad * 4 + r;
                const int col = n0 + wn + j * 16 + l15;
                Sp[(size_t)row * n + col] = acc[i][j][r] * sc;
            }
}

// ---------------------------------------------------------------------------
// Per-row softmax stats: mstat = max, lstat = sum(exp(s-max)). 1 block/row.
// ---------------------------------------------------------------------------
__global__ void rowstat(const float* __restrict__ S, float* __restrict__ mstat,
                        float* __restrict__ lstat, int n) {
    const int row = blockIdx.x;
    const int tid = threadIdx.x;
    const float4* p = (const float4*)(S + (size_t)row * n);
    const int n4 = n >> 2;

    float m = -1e30f;
    for (int i = tid; i < n4; i += 256) {
        float4 v = p[i];
        m = fmaxf(m, fmaxf(fmaxf(v.x, v.y), fmaxf(v.z, v.w)));
    }
    __shared__ float red[256];
    red[tid] = m;
    __syncthreads();
    for (int off = 128; off > 0; off >>= 1) {
        if (tid < off) red[tid] = fmaxf(red[tid], red[tid + off]);
        __syncthreads();
    }
    const float mx = red[0];
    __syncthreads();

    float s = 0.f;
    for (int i = tid; i < n4; i += 256) {
        float4 v = p[i];
        s += expf(v.x - mx) + expf(v.y - mx) + expf(v.z - mx) + expf(v.w - mx);
    }
    red[tid] = s;
    __syncthreads();
    for (int off = 128; off > 0; off >>= 1) {
        if (tid < off) red[tid] += red[tid + off];
        __syncthreads();
    }
    if (tid == 0) { mstat[row] = mx; lstat[row] = red[0]; }
}

// ---------------------------------------------------------------------------
// LayerNorm over 4096-wide rows, in place, float4-vectorized.
// ---------------------------------------------------------------------------
__global__ void layernorm4096(float* __restrict__ h1,
                              const float* __restrict__ g,
                              const float* __restrict__ bta) {
    const int row = blockIdx.x;
    const int tid = threadIdx.x;
    float4* p = (float4*)(h1 + (size_t)row * 4096);
    const float4* g4 = (const float4*)g;
    const float4* b4 = (const float4*)bta;

    float4 vals[4];
    float s = 0.f;
#pragma unroll
    for (int i = 0; i < 4; i++) {
        vals[i] = p[i * 256 + tid];
        s += vals[i].x + vals[i].y + vals[i].z + vals[i].w;
    }

    __shared__ float red[256];
    red[tid] = s;
    __syncthreads();
    for (int off = 128; off > 0; off >>= 1) {
        if (tid < off) red[tid] += red[tid + off];
        __syncthreads();
    }
    const float mu = red[0] * (1.0f / 4096.0f);
    __syncthreads();

    float s2 = 0.f;
#pragma unroll
    for (int i = 0; i < 4; i++) {
        float dx = vals[i].x - mu, dy = vals[i].y - mu,
              dz = vals[i].z - mu, dw = vals[i].w - mu;
        s2 += dx * dx + dy * dy + dz * dz + dw * dw;
    }
    red[tid] = s2;
    __syncthreads();
    for (int off = 128; off > 0; off >>= 1) {
        if (tid < off) red[tid] += red[tid + off];
        __syncthreads();
    }
    const float rstd = rsqrtf(red[0] * (1.0f / 4096.0f) + 1e-5f);

#pragma unroll
    for (int i = 0; i < 4; i++) {
        const int c = i * 256 + tid;
        float4 gv = g4[c], bv = b4[c], o;
        o.x = (vals[i].x - mu) * rstd * gv.x + bv.x;
        o.y = (vals[i].y - mu) * rstd * gv.y + bv.y;
        o.z = (vals[i].z - mu) * rstd * gv.z + bv.z;
        o.w = (vals[i].w - mu) * rstd * gv.w + bv.w;
        p[c] = o;
    }
}

// ---------------------------------------------------------------------------
// A[b,qi,h,r] = (sum_n exp(S[b,h,qi,n]-m) * vmid[b,n,qi*64+r]) / l
// exp applied on LDS load; 4 independent accumulators break the fma chain.
// ---------------------------------------------------------------------------
__global__ void attn_vmid_reduce(const float* __restrict__ S,
                                 const float* __restrict__ mstat,
                                 const float* __restrict__ lstat,
                                 const float* __restrict__ vmid,
                                 float* __restrict__ Abuf, int n) {
    const int b = blockIdx.x >> 6;
    const int qi = blockIdx.x & 63;
    const int tid = threadIdx.x;
    const int h = tid >> 6;
    const int r = tid & 63;

    __shared__ float sA[8 * 1024];
    __shared__ float sm[8], sl[8];
    if (tid < 8) {
        sm[tid] = mstat[((size_t)b * 8 + tid) * 64 + qi];
        sl[tid] = lstat[((size_t)b * 8 + tid) * 64 + qi];
    }
    __syncthreads();
    for (int i = tid; i < 8 * n; i += 512) {
        const int hh = i / n;
        const int ni = i - hh * n;
        sA[hh * n + ni] =
            expf(S[(((size_t)(b * 8 + hh) * 64 + qi)) * n + ni] - sm[hh]);
    }
    __syncthreads();

    const float* vp = vmid + (size_t)b * n * 4096 + qi * 64 + r;
    const float* ap = sA + h * n;
    float a0 = 0.f, a1 = 0.f, a2 = 0.f, a3 = 0.f;
    for (int ni = 0; ni < n; ni += 4) {
        a0 += ap[ni]     * vp[(size_t)ni * 4096];
        a1 += ap[ni + 1] * vp[(size_t)(ni + 1) * 4096];
        a2 += ap[ni + 2] * vp[(size_t)(ni + 2) * 4096];
        a3 += ap[ni + 3] * vp[(size_t)(ni + 3) * 4096];
    }
    Abuf[(size_t)blockIdx.x * 512 + h * 64 + r] =
        ((a0 + a1) + (a2 + a3)) / sl[h];
}

// ---------------------------------------------------------------------------
// out_pre[b,qi,d] = sum_r A[b,qi,h(d),r] * Wc[qi,r,d]  (bf16 output)
// ---------------------------------------------------------------------------
__global__ void apply_wc(const float* __restrict__ Abuf,
                         const float* __restrict__ Wc,
                         ushort_t* __restrict__ out_pre) {
    const int qi = blockIdx.x & 63;
    const int d = threadIdx.x;

    __shared__ float sA[512];
    if (d < 512) sA[d] = Abuf[(size_t)blockIdx.x * 512 + d];
    __syncthreads();

    const int h = d / 96;
    const float* wp = Wc + (size_t)qi * 64 * 768 + d;
    float acc = 0.f;
#pragma unroll
    for (int r = 0; r < 64; r++) acc += sA[h * 64 + r] * wp[(size_t)r * 768];

    out_pre[(size_t)blockIdx.x * 768 + d] = f2b_rne(acc);
}

// ---------------------------------------------------------------------------
extern "C" void kernel_launch(void* const* d_in, const int* in_sizes, int n_in,
                              void* d_out, int out_size, void* d_ws, size_t ws_size,
                              hipStream_t stream) {
    const float* x       = (const float*)d_in[0];
    const float* context = (const float*)d_in[1];
    const float* Wq      = (const float*)d_in[2];
    const float* Wk      = (const float*)d_in[3];
    const float* Wv1     = (const float*)d_in[4];
    const float* ln_g    = (const float*)d_in[5];
    const float* ln_b    = (const float*)d_in[6];
    const float* Wc      = (const float*)d_in[7];
    const float* Wout    = (const float*)d_in[8];
    float* out = (float*)d_out;

    const int b = in_sizes[0] / (64 * 768);
    const int n = in_sizes[1] / (b * 768);
    const int M  = b * 64;    // 256
    const int Mn = b * n;     // 4096

    float* ws = (float*)d_ws;
    size_t off = 0;
    float* h1    = ws + off;  off += (size_t)Mn * 4096;
    float* S     = ws + off;  off += (size_t)b * 8 * 64 * n;
    float* Abuf  = ws + off;  off += (size_t)M * 512;
    float* mstat = ws + off;  off += (size_t)b * 8 * 64;
    float* lstat = ws + off;  off += (size_t)b * 8 * 64;

    ushort_t* us = (ushort_t*)(ws + off);
    size_t uo = 0;
    ushort_t* x_b    = us + uo;  uo += (size_t)M * 768;
    ushort_t* ctx_b  = us + uo;  uo += (size_t)Mn * 768;
    ushort_t* qb     = us + uo;  uo += (size_t)M * 768;
    ushort_t* kb     = us + uo;  uo += (size_t)Mn * 768;
    ushort_t* Wq_t   = us + uo;  uo += (size_t)768 * 768;
    ushort_t* Wk_t   = us + uo;  uo += (size_t)768 * 768;
    ushort_t* Wv1_t  = us + uo;  uo += (size_t)4096 * 768;
    ushort_t* Wout_t = us + uo;  uo += (size_t)768 * 768;
    ushort_t* outp_b = us + uo;  uo += (size_t)M * 768;

    const dim3 tblk(32, 8);

    // bf16 conversions
    {
        int n4 = M * 768 / 4;
        f2b_flat<<<(n4 + 255) / 256, 256, 0, stream>>>(x, x_b, n4);
        n4 = Mn * 768 / 4;
        f2b_flat<<<(n4 + 255) / 256, 256, 0, stream>>>(context, ctx_b, n4);
        f2b_t<<<dim3(768 / 32, 768 / 32), tblk, 0, stream>>>(Wq, Wq_t, 768, 768);
        f2b_t<<<dim3(768 / 32, 768 / 32), tblk, 0, stream>>>(Wk, Wk_t, 768, 768);
        f2b_t<<<dim3(4096 / 32, 768 / 32), tblk, 0, stream>>>(Wv1, Wv1_t, 768, 4096);
        f2b_t<<<dim3(768 / 32, 768 / 32), tblk, 0, stream>>>(Wout, Wout_t, 768, 768);
    }

    // q = x @ Wq   (bf16 out)
    gemm_bt<true><<<dim3(768 / 128, M / 128), 256, 0, stream>>>(x_b, Wq_t, qb, M, 768, 768);
    // k = context @ Wk  (bf16 out)
    gemm_bt<true><<<dim3(768 / 128, Mn / 128), 256, 0, stream>>>(ctx_b, Wk_t, kb, Mn, 768, 768);
    // h1 = context @ Wv1  (fp32 out)
    gemm_bt<false><<<dim3(4096 / 128, Mn / 128), 256, 0, stream>>>(ctx_b, Wv1_t, h1, Mn, 4096, 768);
    // LayerNorm in place -> vmid
    layernorm4096<<<Mn, 256, 0, stream>>>(h1, ln_g, ln_b);
    // S = QK^T * scale   [b,h,64,n]
    scores_mfma<<<dim3(n / 128, b * 8), 256, 0, stream>>>(qb, kb, S, n);
    // per-row max & sumexp
    rowstat<<<b * 8 * 64, 256, 0, stream>>>(S, mstat, lstat, n);
    // A = softmax(S) . vmid  (normalization folded in)
    attn_vmid_reduce<<<b * 64, 512, 0, stream>>>(S, mstat, lstat, h1, Abuf, n);
    // out_pre = A . Wc (bf16 out)
    apply_wc<<<b * 64, 768, 0, stream>>>(Abuf, Wc, outp_b);
    // out = out_pre @ Wout
    gemm_bt<false><<<dim3(768 / 128, M / 128), 256, 0, stream>>>(outp_b, Wout_t, out, M, 768, 768);
}